// Round 2
// baseline (342.512 us; speedup 1.0000x reference)
//
#include <hip/hip_runtime.h>
#include <stdint.h>

// TinyMod fused v2: register-accumulated stage-2, 1024-thr WG (16 waves), BT=16.
// Phase A: 4 m-chunks of 32: stage x -> LDS, stage1 MFMA -> ylds, stage2 K=32
// MFMA accumulate into 64 VGPRs. 2 barriers/chunk.
// Phase B: 8 n-tiles: acc -> wchunk (dbuf) -> stage3 MFMA -> out. 1 barrier/tile.

#define BT    16
#define NTHR  1024
#define GRID  512      // 8192 / BT
#define IDIM  4096
#define ODIM  4096

typedef __attribute__((ext_vector_type(8))) __bf16 bf16x8;
typedef __attribute__((ext_vector_type(4))) float  floatx4;

union BF8 { uint32_t w[4]; unsigned short h[8]; bf16x8 v; };

__device__ __forceinline__ unsigned short f2bf(float f) {
    uint32_t u = __builtin_bit_cast(uint32_t, f);
    u += 0x7fffu + ((u >> 16) & 1u);   // RNE
    return (unsigned short)(u >> 16);
}

// LDS pitches (bf16 elems), chosen for uniform start-bank coverage:
// xs [m][bt][i]:  bt-pitch 40 (20 dw), m-pitch 656 (328 dw, %32=8)
//   staging b128 writes: starts {8*smp + 20*sbt} -> all 8 mult-4 classes, 8 lanes each (optimal)
//   A-frag b128 reads:   starts {20*l15 + 4*grp} -> uniform (optimal)
// ys [c][bt][m]:  bt-pitch 40, c-pitch 648 (324 dw, %32=4)
//   b64 y-writes ~2x excess (4 instr/wave/iter); A-frag b128 reads uniform (optimal)
// wc [n][bt][c]:  bt-pitch 34 (17 dw), n-pitch 546 (273 dw, odd) -> ~2-way (free)
#define XP_BT 40
#define XP_M  656
#define YP_BT 40
#define YP_C  648
#define WP_BT 34
#define WP_N  546
#define WBUF  8736     // 16 * WP_N

template<bool WBF16>
__global__ __launch_bounds__(NTHR, 4)
void tinymod_fused(const float* __restrict__ x,
                   const float* __restrict__ W_in,
                   const float* __restrict__ b_in,
                   const void*  __restrict__ wmods,
                   const float* __restrict__ b_mods,
                   const float* __restrict__ W_out,
                   const float* __restrict__ b_out,
                   float* __restrict__ out)
{
    __shared__ unsigned short xs[32 * XP_M] __attribute__((aligned(16)));  // 41984 B
    __shared__ unsigned short ys[32 * YP_C] __attribute__((aligned(16)));  // 41472 B
    __shared__ unsigned short wc[2 * WBUF]  __attribute__((aligned(16)));  // 34944 B

    const int tid  = threadIdx.x;
    const int w    = tid >> 6;          // wave 0..15
    const int lane = tid & 63;
    const int l15  = lane & 15;
    const int grp  = lane >> 4;         // 0..3
    const int row0 = blockIdx.x * BT;

    // phase-A wave roles: stage1 -> (m-quad mq, c-half cc); stage2 -> c = 2w+{0,1}
    const int cc = w >> 3, mq = w & 7;

    // stage-1 B fragment (wave's c-half only) + bias
    BF8 winf;
    {
        const float* p = W_in + (l15 + 16*cc) * 32 + grp * 8;  // B[k=i][col=c]
        #pragma unroll
        for (int j = 0; j < 8; j++) winf.h[j] = f2bf(p[j]);
    }
    const float bin = b_in[l15 + 16*cc];

    // staging role: thread -> (m=smp, bt=sbt, i-half sih), 16 strided dword loads/chunk
    const int smp = tid & 31, sbt = (tid >> 5) & 15, sih = tid >> 9;
    const float* xb = x + (row0 + sbt) * IDIM + smp + sih * (16 * 128);

    floatx4 acc[2][8];
    #pragma unroll
    for (int a = 0; a < 2; a++)
        #pragma unroll
        for (int b = 0; b < 8; b++) acc[a][b] = (floatx4){0.f, 0.f, 0.f, 0.f};

    const unsigned short* __restrict__ wm16 = (const unsigned short*)wmods;
    const float*          __restrict__ wm32 = (const float*)wmods;
    int wmb[2];
    #pragma unroll
    for (int c2 = 0; c2 < 2; c2++)
        wmb[c2] = ((2*w + c2) * 128 + l15) * 128 + grp * 8;   // + nt*2048 + mc*32

    float xr[16];
    #pragma unroll
    for (int j = 0; j < 16; j++) xr[j] = xb[j * 128];

    // ---------------- Phase A ----------------
    #pragma unroll
    for (int mc = 0; mc < 4; mc++) {
        // staged regs -> xs (two b128 per thread)
        #pragma unroll
        for (int p = 0; p < 2; p++) {
            BF8 t;
            #pragma unroll
            for (int j = 0; j < 8; j++) t.h[j] = f2bf(xr[p*8 + j]);
            uint4 v4; v4.x = t.w[0]; v4.y = t.w[1]; v4.z = t.w[2]; v4.w = t.w[3];
            *(uint4*)&xs[smp*XP_M + sbt*XP_BT + sih*16 + p*8] = v4;
        }
        __syncthreads();   // bar A: xs ready (also fences prior stage-2 ys reads)

        // stage 1: wave computes y for m = mq*4+k (k=0..3), c-half cc
        unsigned short yh[4][4];
        #pragma unroll
        for (int k = 0; k < 4; k++) {
            BF8 a;
            const uint4 av = *(const uint4*)&xs[(mq*4 + k)*XP_M + l15*XP_BT + grp*8];
            a.w[0] = av.x; a.w[1] = av.y; a.w[2] = av.z; a.w[3] = av.w;
            floatx4 y = {0.f, 0.f, 0.f, 0.f};
            y = __builtin_amdgcn_mfma_f32_16x16x32_bf16(a.v, winf.v, y, 0, 0, 0);
            #pragma unroll
            for (int r = 0; r < 4; r++) yh[k][r] = f2bf(y[r] + bin);
        }
        #pragma unroll
        for (int r = 0; r < 4; r++) {
            uint2 pk;
            pk.x = (uint32_t)yh[0][r] | ((uint32_t)yh[1][r] << 16);
            pk.y = (uint32_t)yh[2][r] | ((uint32_t)yh[3][r] << 16);
            *(uint2*)&ys[(l15 + 16*cc)*YP_C + (grp*4 + r)*YP_BT + mq*4] = pk;
        }
        __syncthreads();   // bar B: ys ready

        // prefetch next x chunk (in flight across all of stage 2)
        float xr2[16];
        if (mc < 3) {
            #pragma unroll
            for (int j = 0; j < 16; j++) xr2[j] = xb[j*128 + (mc + 1)*32];
        }

        // stage 2: wave owns c = 2w+{0,1}; K=32 chunk accumulate
        #pragma unroll
        for (int c2 = 0; c2 < 2; c2++) {
            BF8 a;
            const uint4 av = *(const uint4*)&ys[(2*w + c2)*YP_C + l15*YP_BT + grp*8];
            a.w[0] = av.x; a.w[1] = av.y; a.w[2] = av.z; a.w[3] = av.w;
            #pragma unroll
            for (int nt = 0; nt < 8; nt++) {
                BF8 b;
                if (WBF16) {
                    const uint4 bv = *(const uint4*)&wm16[wmb[c2] + nt*2048 + mc*32];
                    b.w[0] = bv.x; b.w[1] = bv.y; b.w[2] = bv.z; b.w[3] = bv.w;
                } else {
                    const float* wp = wm32 + wmb[c2] + nt*2048 + mc*32;
                    #pragma unroll
                    for (int j = 0; j < 8; j++) b.h[j] = f2bf(wp[j]);
                }
                acc[c2][nt] = __builtin_amdgcn_mfma_f32_16x16x32_bf16(a.v, b.v, acc[c2][nt], 0, 0, 0);
            }
        }
        if (mc < 3) {
            #pragma unroll
            for (int j = 0; j < 16; j++) xr[j] = xr2[j];
        }
    }

    // ---------------- Phase B ----------------
    BF8 woutf[2];
    #pragma unroll
    for (int oc = 0; oc < 2; oc++) {
        const float* q = W_out + (l15 + 16*oc) * 32 + grp * 8;  // B[k=c][col=o]
        #pragma unroll
        for (int j = 0; j < 8; j++) woutf[oc].h[j] = f2bf(q[j]);
    }
    const float bo0 = b_out[l15], bo1 = b_out[16 + l15];
    float bm[2][8];
    #pragma unroll
    for (int c2 = 0; c2 < 2; c2++)
        #pragma unroll
        for (int nt = 0; nt < 8; nt++)
            bm[c2][nt] = b_mods[(2*w + c2)*128 + nt*16 + l15];

    float* outb = out + (long)row0 * ODIM;
    #pragma unroll
    for (int nt = 0; nt < 8; nt++) {
        const int buf = (nt & 1) * WBUF;
        // w (+bias) -> wchunk: lane holds (n=l15, bt=grp*4+r), c-pair at 2w
        #pragma unroll
        for (int r = 0; r < 4; r++) {
            const uint32_t pk = (uint32_t)f2bf(acc[0][nt][r] + bm[0][nt])
                              | ((uint32_t)f2bf(acc[1][nt][r] + bm[1][nt]) << 16);
            *(uint32_t*)&wc[buf + l15*WP_N + (grp*4 + r)*WP_BT + 2*w] = pk;
        }
        __syncthreads();
        // stage 3: wave -> n-within-tile = w; K = c = 32 in one MFMA
        BF8 a;
        #pragma unroll
        for (int j = 0; j < 4; j++)
            a.w[j] = *(const uint32_t*)&wc[buf + w*WP_N + l15*WP_BT + grp*8 + j*2];
        #pragma unroll
        for (int oc = 0; oc < 2; oc++) {
            floatx4 v = {0.f, 0.f, 0.f, 0.f};
            v = __builtin_amdgcn_mfma_f32_16x16x32_bf16(a.v, woutf[oc].v, v, 0, 0, 0);
            const float bo = oc ? bo1 : bo0;
            float* po = outb + (nt*16 + w)*32 + oc*16 + l15;
            #pragma unroll
            for (int r = 0; r < 4; r++)
                po[(grp*4 + r) * ODIM] = v[r] + bo;   // 64-B segments
        }
    }
}

// prologue: W_mods fp32 -> bf16 into workspace (2 MiB -> 1 MiB, L2/L3 resident)
__global__ void wmods_to_bf16(const float* __restrict__ wsrc, unsigned short* __restrict__ o) {
    const int i = (blockIdx.x * 256 + threadIdx.x) * 4;
    const float4 f = *(const float4*)(wsrc + i);
    uint2 pk;
    pk.x = (uint32_t)f2bf(f.x) | ((uint32_t)f2bf(f.y) << 16);
    pk.y = (uint32_t)f2bf(f.z) | ((uint32_t)f2bf(f.w) << 16);
    *(uint2*)(o + i) = pk;
}

extern "C" void kernel_launch(void* const* d_in, const int* in_sizes, int n_in,
                              void* d_out, int out_size, void* d_ws, size_t ws_size,
                              hipStream_t stream)
{
    const float* x     = (const float*)d_in[0];
    const float* W_in  = (const float*)d_in[1];
    const float* b_in  = (const float*)d_in[2];
    const float* Wm    = (const float*)d_in[3];
    const float* b_m   = (const float*)d_in[4];
    const float* W_out = (const float*)d_in[5];
    const float* b_out = (const float*)d_in[6];
    float* out = (float*)d_out;

    const size_t wm_elems = 32u * 128u * 128u;   // 524288
    if (ws_size >= wm_elems * sizeof(unsigned short)) {
        unsigned short* wbf = (unsigned short*)d_ws;
        wmods_to_bf16<<<(int)(wm_elems / (256 * 4)), 256, 0, stream>>>(Wm, wbf);
        tinymod_fused<true><<<GRID, NTHR, 0, stream>>>(x, W_in, b_in, (const void*)wbf,
                                                       b_m, W_out, b_out, out);
    } else {
        tinymod_fused<false><<<GRID, NTHR, 0, stream>>>(x, W_in, b_in, (const void*)Wm,
                                                        b_m, W_out, b_out, out);
    }
}